// Round 1
// baseline (2612.193 us; speedup 1.0000x reference)
//
#include <hip/hip_runtime.h>
#include <hip/hip_bf16.h>

// Model: bipartite GNN (computer graph NC=50000 / task graph NT=64), 2 rounds of
// gconv + cross-mixing through placement, then group segment-sum + final [GC,GT] matmul.
// Key algebraic rewrites vs reference:
//  1) msg = tanh(concat(x[src],e)@Wm+b)  ->  xm = x@Wm_top per NODE (6.5GF not 52GF),
//     per edge only the 8-wide edge part + gather + atomic scatter-add.
//  2) concat(a,b)@W -> a@W_top + b@W_bot  (dual-GEMM kernel).
//  3) segment_sum(c@cf_W+cf_b) @ (segment_sum(t@tf_W+tf_b)).T
//     -> out[g,j] = csum[g]·M[:,j] + n_g*cbdot[j],  M = cf_W@gtemb.T  (saves 204MB + 26GF).

constexpr int NCn = 50000, NTn = 64, ECn = 400000, ETn = 2048;
constexpr int GCn = 10000, GTn = 16;
constexpr int NH  = 256, EHn = 8, EMBn = 1024;

// ---- node feature init (computer): c = tanh(concat(cfeats, op_emb[ctype]) @ W + b)
__global__ void k_cinit(const float* __restrict__ cfeats, const int* __restrict__ ctypes,
                        const float* __restrict__ op_emb, const float* __restrict__ W,
                        const float* __restrict__ b, float* __restrict__ out) {
    int nc = blockIdx.x, col = threadIdx.x;
    __shared__ float s[32];
    if (col < 24) s[col] = cfeats[nc * 24 + col];
    else if (col < 32) s[col] = op_emb[ctypes[nc] * 8 + (col - 24)];
    __syncthreads();
    float acc = b[col];
#pragma unroll
    for (int k = 0; k < 32; k++) acc += s[k] * W[k * NH + col];
    out[nc * NH + col] = tanhf(acc);
}

// ---- node feature init (task): t = tanh(tfeats @ W + b), tfeats [NT,16]
__global__ void k_tinit(const float* __restrict__ tfeats, const float* __restrict__ W,
                        const float* __restrict__ b, float* __restrict__ out) {
    int n = blockIdx.x, col = threadIdx.x;
    __shared__ float s[16];
    if (col < 16) s[col] = tfeats[n * 16 + col];
    __syncthreads();
    float acc = b[col];
#pragma unroll
    for (int k = 0; k < 16; k++) acc += s[k] * W[k * NH + col];
    out[n * NH + col] = tanhf(acc);
}

// ---- edge feature init: eh = tanh(ef[E,4] @ W[4,8] + b[8])
__global__ void k_einit(const float* __restrict__ ef, const float* __restrict__ W,
                        const float* __restrict__ b, float* __restrict__ out, int E) {
    int e = blockIdx.x * blockDim.x + threadIdx.x;
    if (e >= E) return;
    float f0 = ef[e * 4], f1 = ef[e * 4 + 1], f2 = ef[e * 4 + 2], f3 = ef[e * 4 + 3];
#pragma unroll
    for (int j = 0; j < 8; j++) {
        float acc = b[j] + f0 * W[j] + f1 * W[8 + j] + f2 * W[16 + j] + f3 * W[24 + j];
        out[e * 8 + j] = tanhf(acc);
    }
}

// ---- generic (dual) GEMM over 256-wide states:
// out[n,col] = act( A[n]·W1[:,col] + (HASB ? B[n]·W2[:,col] : 0) + bias[col] )
// R rows per block, 256 threads = 256 cols. Shared staged transposed (k-major,
// row-minor as float4) so the inner loop does ds_read_b128 broadcasts.
template <int R, bool HASB, bool TANH>
__global__ void k_gemm256(const float* __restrict__ A, const float* __restrict__ W1,
                          const float* __restrict__ B, const float* __restrict__ W2,
                          const float* __restrict__ bias, float* __restrict__ out, int N) {
    constexpr int RV = R / 4;
    int row0 = blockIdx.x * R, col = threadIdx.x;
    __shared__ float4 sA[NH * RV];
    __shared__ float4 sB[HASB ? NH * RV : 1];
#pragma unroll
    for (int r = 0; r < R; r++) {
        int n = row0 + r;
        float va = (n < N) ? A[(size_t)n * NH + col] : 0.f;
        ((float*)sA)[col * R + r] = va;   // layout s[k][r]
        if constexpr (HASB) {
            float vb = (n < N) ? B[(size_t)n * NH + col] : 0.f;
            ((float*)sB)[col * R + r] = vb;
        }
    }
    __syncthreads();
    float acc[R];
    float bb = bias ? bias[col] : 0.f;
#pragma unroll
    for (int r = 0; r < R; r++) acc[r] = bb;
    for (int k = 0; k < NH; k++) {
        float w = W1[k * NH + col];
#pragma unroll
        for (int v = 0; v < RV; v++) {
            float4 a = sA[k * RV + v];
            acc[4 * v + 0] += a.x * w; acc[4 * v + 1] += a.y * w;
            acc[4 * v + 2] += a.z * w; acc[4 * v + 3] += a.w * w;
        }
    }
    if constexpr (HASB) {
        for (int k = 0; k < NH; k++) {
            float w = W2[k * NH + col];
#pragma unroll
            for (int v = 0; v < RV; v++) {
                float4 a = sB[k * RV + v];
                acc[4 * v + 0] += a.x * w; acc[4 * v + 1] += a.y * w;
                acc[4 * v + 2] += a.z * w; acc[4 * v + 3] += a.w * w;
            }
        }
    }
#pragma unroll
    for (int r = 0; r < R; r++) {
        int n = row0 + r;
        if (n < N) { float o = acc[r]; out[(size_t)n * NH + col] = TANH ? tanhf(o) : o; }
    }
}

// ---- per-edge message + scatter: agg[dst] += tanh(xm[src] + eh[e]@Wme + bm)
template <int EPB>
__global__ void k_scatter(const float* __restrict__ xm, const float* __restrict__ eh,
                          const int* __restrict__ src, const int* __restrict__ dst,
                          const float* __restrict__ Wme /* rows 256..263 of Wm: [8][256] */,
                          const float* __restrict__ bm, float* __restrict__ agg, int E) {
    int e0 = blockIdx.x * EPB, col = threadIdx.x;
    __shared__ float s_eh[EPB][8];
    __shared__ int s_src[EPB], s_dst[EPB];
    int ne = min(EPB, E - e0);
    if (col < ne * 8) s_eh[col >> 3][col & 7] = eh[(size_t)e0 * 8 + col];
    if (col < ne) { s_src[col] = src[e0 + col]; s_dst[col] = dst[e0 + col]; }
    __syncthreads();
    float wme[8];
#pragma unroll
    for (int k = 0; k < 8; k++) wme[k] = Wme[k * NH + col];
    float bb = bm[col];
    for (int e = 0; e < ne; e++) {
        float em = bb;
#pragma unroll
        for (int k = 0; k < 8; k++) em += s_eh[e][k] * wme[k];
        float msg = tanhf(xm[(size_t)s_src[e] * NH + col] + em);
        atomicAdd(&agg[(size_t)s_dst[e] * NH + col], msg);
    }
}

// ---- Pt = placement[NC,64] @ t1[64,256]  (R rows per block)
template <int R>
__global__ void k_pt(const float* __restrict__ P, const float* __restrict__ t1,
                     float* __restrict__ out, int N) {
    int row0 = blockIdx.x * R, col = threadIdx.x;
    __shared__ float sP[R][64];
    for (int i = threadIdx.x; i < R * 64; i += 256) {
        int r = i >> 6, k = i & 63;
        int n = row0 + r;
        sP[r][k] = (n < N) ? P[(size_t)n * 64 + k] : 0.f;
    }
    __syncthreads();
    float acc[R] = {};
    for (int k = 0; k < 64; k++) {
        float w = t1[k * NH + col];
#pragma unroll
        for (int r = 0; r < R; r++) acc[r] += sP[r][k] * w;
    }
#pragma unroll
    for (int r = 0; r < R; r++) {
        int n = row0 + r;
        if (n < N) out[(size_t)n * NH + col] = acc[r];
    }
}

// ---- Ptc = placement.T @ c : [64,256], block-partial accumulators + atomics
__global__ void k_ptc(const float* __restrict__ P, const float* __restrict__ c,
                      float* __restrict__ out /* [64][256], pre-zeroed */, int N) {
    int col = threadIdx.x;
    int per = (N + gridDim.x - 1) / gridDim.x;
    int n0 = blockIdx.x * per, n1 = min(N, n0 + per);
    float acc[64] = {};
    __shared__ __align__(16) float sP[64];
    for (int n = n0; n < n1; n++) {
        if (col < 64) sP[col] = P[(size_t)n * 64 + col];
        __syncthreads();
        float v = c[(size_t)n * NH + col];
        const float4* sP4 = (const float4*)sP;
#pragma unroll
        for (int k4 = 0; k4 < 16; k4++) {
            float4 p = sP4[k4];
            acc[4 * k4 + 0] += p.x * v; acc[4 * k4 + 1] += p.y * v;
            acc[4 * k4 + 2] += p.z * v; acc[4 * k4 + 3] += p.w * v;
        }
        __syncthreads();
    }
#pragma unroll
    for (int k = 0; k < 64; k++) atomicAdd(&out[k * NH + col], acc[k]);
}

// ---- group segment-sum: gsum[gid[n]] += x[n], gcnt[gid[n]] += 1
__global__ void k_gsum(const float* __restrict__ x, const int* __restrict__ gid,
                       float* __restrict__ gsum, float* __restrict__ gcnt, int N) {
    int n = blockIdx.x, col = threadIdx.x;
    int g = gid[n];
    atomicAdd(&gsum[(size_t)g * NH + col], x[(size_t)n * NH + col]);
    if (col == 0) atomicAdd(&gcnt[g], 1.0f);
}

// ---- gtemb[g] = tsum[g] @ tf_W + tcnt[g]*tf_b   [GT,1024]
__global__ void k_gtemb(const float* __restrict__ tsum, const float* __restrict__ tcnt,
                        const float* __restrict__ W, const float* __restrict__ b,
                        float* __restrict__ out) {
    int g = blockIdx.x;
    __shared__ float s[NH];
    s[threadIdx.x] = tsum[g * NH + threadIdx.x];
    __syncthreads();
    float cnt = tcnt[g];
    for (int col = threadIdx.x; col < EMBn; col += 256) {
        float acc = cnt * b[col];
        for (int k = 0; k < NH; k++) acc += s[k] * W[k * EMBn + col];
        out[g * EMBn + col] = acc;
    }
}

// ---- M[k][j] = cf_W[k,:]·gtemb[j,:]  (M = cf_W @ gtemb.T, [256,16]); cbdot[j]=cf_b·gtemb[j]
__global__ void k_M(const float* __restrict__ cf_W, const float* __restrict__ cf_b,
                    const float* __restrict__ gtemb, float* __restrict__ M,
                    float* __restrict__ cbdot) {
    int j = blockIdx.x, r = threadIdx.x;
    __shared__ float sg[EMBn];
    for (int k = threadIdx.x; k < EMBn; k += 256) sg[k] = gtemb[j * EMBn + k];
    __syncthreads();
    float acc = 0.f;
    for (int k = 0; k < EMBn; k++) acc += cf_W[(size_t)r * EMBn + k] * sg[k];
    M[r * GTn + j] = acc;
    if (r == 0) {
        float a = 0.f;
        for (int k = 0; k < EMBn; k++) a += cf_b[k] * sg[k];
        cbdot[j] = a;
    }
}

// ---- out[g,j] = csum[g]·M[:,j] + ccnt[g]*cbdot[j]  (16 groups x 16 cols per block)
__global__ void k_out(const float* __restrict__ csum, const float* __restrict__ ccnt,
                      const float* __restrict__ M, const float* __restrict__ cbdot,
                      float* __restrict__ out, int G) {
    __shared__ float sM[NH * GTn];
    __shared__ float sb[GTn];
    for (int i = threadIdx.x; i < NH * GTn; i += 256) sM[i] = M[i];
    if (threadIdx.x < GTn) sb[threadIdx.x] = cbdot[threadIdx.x];
    __syncthreads();
    int gl = threadIdx.x >> 4, j = threadIdx.x & 15;
    int g = blockIdx.x * 16 + gl;
    if (g >= G) return;
    float acc = ccnt[g] * sb[j];
    for (int k = 0; k < NH; k++) acc += csum[(size_t)g * NH + k] * sM[k * GTn + j];
    out[g * GTn + j] = acc;
}

extern "C" void kernel_launch(void* const* d_in, const int* in_sizes, int n_in,
                              void* d_out, int out_size, void* d_ws, size_t ws_size,
                              hipStream_t stream) {
    const float* cfeats   = (const float*)d_in[0];
    const float* cedge    = (const float*)d_in[1];
    const float* tfeats   = (const float*)d_in[2];
    const float* tedge    = (const float*)d_in[3];
    const float* placement= (const float*)d_in[4];
    // d_in[5] runtime_stats: unused by reference
    const float* op_emb   = (const float*)d_in[6];
    const float* cn_W = (const float*)d_in[7];  const float* cn_b = (const float*)d_in[8];
    const float* ce_W = (const float*)d_in[9];  const float* ce_b = (const float*)d_in[10];
    const float* tn_W = (const float*)d_in[11]; const float* tn_b = (const float*)d_in[12];
    const float* te_W = (const float*)d_in[13]; const float* te_b = (const float*)d_in[14];
    const float* cg_Wmsg = (const float*)d_in[15]; const float* cg_bmsg = (const float*)d_in[16];
    const float* cg_Wupd = (const float*)d_in[17]; const float* cg_bupd = (const float*)d_in[18];
    const float* tg_Wmsg = (const float*)d_in[19]; const float* tg_bmsg = (const float*)d_in[20];
    const float* tg_Wupd = (const float*)d_in[21]; const float* tg_bupd = (const float*)d_in[22];
    const float* cc_W = (const float*)d_in[23]; const float* cc_b = (const float*)d_in[24];
    const float* tc_W = (const float*)d_in[25]; const float* tc_b = (const float*)d_in[26];
    const float* cf_W = (const float*)d_in[27]; const float* cf_b = (const float*)d_in[28];
    const float* tf_W = (const float*)d_in[29]; const float* tf_b = (const float*)d_in[30];
    const int* ctypes = (const int*)d_in[31];
    const int* c_src = (const int*)d_in[32]; const int* c_dst = (const int*)d_in[33];
    const int* t_src = (const int*)d_in[34]; const int* t_dst = (const int*)d_in[35];
    const int* cgroup = (const int*)d_in[36]; const int* tgroup = (const int*)d_in[37];
    float* out = (float*)d_out;

    float* ws = (float*)d_ws;
    size_t off = 0;
    auto alloc = [&](size_t n) { float* p = ws + off; off += n; return p; };
    float* bufA = alloc((size_t)NCn * NH);
    float* bufB = alloc((size_t)NCn * NH);
    float* bufC = alloc((size_t)NCn * NH);
    float* ce   = alloc((size_t)ECn * EHn);
    float* teh  = alloc((size_t)ETn * EHn);
    float* t0   = alloc(NTn * NH);
    float* t1   = alloc(NTn * NH);
    float* tm   = alloc(NTn * NH);
    float* aggt = alloc(NTn * NH);
    float* ptc  = alloc(NTn * NH);
    float* csum = alloc((size_t)GCn * NH);
    float* ccnt = alloc(GCn);
    float* tsum = alloc(GTn * NH);
    float* tcnt = alloc(GTn);
    float* gtemb= alloc(GTn * EMBn);
    float* Mm   = alloc(NH * GTn);
    float* cbdot= alloc(GTn);
    (void)ws_size; (void)in_sizes; (void)n_in; (void)out_size;

    // ---- feature encoders
    k_cinit<<<NCn, 256, 0, stream>>>(cfeats, ctypes, op_emb, cn_W, cn_b, bufA);
    k_einit<<<(ECn + 255) / 256, 256, 0, stream>>>(cedge, ce_W, ce_b, ce, ECn);
    k_tinit<<<NTn, 256, 0, stream>>>(tfeats, tn_W, tn_b, t0);
    k_einit<<<(ETn + 255) / 256, 256, 0, stream>>>(tedge, te_W, te_b, teh, ETn);

    float* X = bufA; float* Y = bufB; float* Z = bufC;  // X holds current c
    for (int i = 0; i < 2; i++) {
        const float* Wmx = cg_Wmsg + (size_t)i * 264 * NH;
        const float* Wme = Wmx + 256 * NH;
        const float* bm  = cg_bmsg + i * NH;
        const float* Wut = cg_Wupd + (size_t)i * 512 * NH;
        const float* Wub = Wut + 256 * NH;
        const float* bu  = cg_bupd + i * NH;
        const float* tWmx = tg_Wmsg + (size_t)i * 264 * NH;
        const float* tWme = tWmx + 256 * NH;
        const float* tbm  = tg_bmsg + i * NH;
        const float* tWut = tg_Wupd + (size_t)i * 512 * NH;
        const float* tWub = tWut + 256 * NH;
        const float* tbu  = tg_bupd + i * NH;
        const float* ccT = cc_W + (size_t)i * 512 * NH; const float* ccB = ccT + 256 * NH;
        const float* ccb = cc_b + i * NH;
        const float* tcT = tc_W + (size_t)i * 512 * NH; const float* tcB = tcT + 256 * NH;
        const float* tcb = tc_b + i * NH;

        // computer-graph conv: xm=Y, agg=Z, c_new=Y (xm consumed by scatter)
        k_gemm256<8, false, false><<<NCn / 8, 256, 0, stream>>>(X, Wmx, nullptr, nullptr, nullptr, Y, NCn);
        hipMemsetAsync(Z, 0, (size_t)NCn * NH * 4, stream);
        k_scatter<16><<<ECn / 16, 256, 0, stream>>>(Y, ce, c_src, c_dst, Wme, bm, Z, ECn);
        k_gemm256<8, true, true><<<NCn / 8, 256, 0, stream>>>(X, Wut, Z, Wub, bu, Y, NCn);
        // task-graph conv
        k_gemm256<8, false, false><<<NTn / 8, 256, 0, stream>>>(t0, tWmx, nullptr, nullptr, nullptr, tm, NTn);
        hipMemsetAsync(aggt, 0, (size_t)NTn * NH * 4, stream);
        k_scatter<16><<<ETn / 16, 256, 0, stream>>>(tm, teh, t_src, t_dst, tWme, tbm, aggt, ETn);
        k_gemm256<8, true, true><<<NTn / 8, 256, 0, stream>>>(t0, tWut, aggt, tWub, tbu, t1, NTn);
        // cross (computer): Pt into X (old c consumed), result into Z (agg consumed)
        k_pt<8><<<NCn / 8, 256, 0, stream>>>(placement, t1, X, NCn);
        k_gemm256<8, true, true><<<NCn / 8, 256, 0, stream>>>(Y, ccT, X, ccB, ccb, Z, NCn);
        // cross (task): Ptc = P.T @ c_cross, result into t0
        hipMemsetAsync(ptc, 0, NTn * NH * 4, stream);
        k_ptc<<<256, 256, 0, stream>>>(placement, Z, ptc, NCn);
        k_gemm256<8, true, true><<<NTn / 8, 256, 0, stream>>>(t1, tcT, ptc, tcB, tcb, t0, NTn);
        // rotate buffers: new c is Z
        float* tmp = X; X = Z; Z = Y; Y = tmp;
    }

    // ---- fused tail: segment sums first (linear), then tiny projections
    hipMemsetAsync(csum, 0, (size_t)GCn * NH * 4, stream);
    hipMemsetAsync(ccnt, 0, GCn * 4, stream);
    hipMemsetAsync(tsum, 0, GTn * NH * 4, stream);
    hipMemsetAsync(tcnt, 0, GTn * 4, stream);
    k_gsum<<<NCn, 256, 0, stream>>>(X, cgroup, csum, ccnt, NCn);
    k_gsum<<<NTn, 256, 0, stream>>>(t0, tgroup, tsum, tcnt, NTn);
    k_gtemb<<<GTn, 256, 0, stream>>>(tsum, tcnt, tf_W, tf_b, gtemb);
    k_M<<<GTn, 256, 0, stream>>>(cf_W, cf_b, gtemb, Mm, cbdot);
    k_out<<<GCn / 16, 256, 0, stream>>>(csum, ccnt, Mm, cbdot, out, GCn);
}